// Round 8
// baseline (367.800 us; speedup 1.0000x reference)
//
#include <hip/hip_runtime.h>
#include <hip/hip_bf16.h>
#include <math.h>

#define S_LEN   2048
#define HIDDEN  2048
#define NHEADS  16
#define NKVH    4
#define HDIM    128

typedef short  short8  __attribute__((ext_vector_type(8)));
typedef float  floatx4 __attribute__((ext_vector_type(4)));
typedef __hip_bfloat16 bf16;

__device__ inline void async_copy16(const void* g, void* l) {
  __builtin_amdgcn_global_load_lds((__attribute__((address_space(1))) void*)(g),
                                   (__attribute__((address_space(3))) void*)(l),
                                   16, 0, 0);
}

__device__ inline unsigned short cvt1(float x) {
  bf16 t = __float2bfloat16(x);
  return *reinterpret_cast<unsigned short*>(&t);
}
__device__ inline float us2f(unsigned short u) {
  unsigned int v = ((unsigned int)u) << 16;
  return *reinterpret_cast<float*>(&v);
}

// RoPE table: rt[s*64 + j] = (cos, sin)(s * 10000^(-j/64))
__global__ __launch_bounds__(256) void rope_table(float2* __restrict__ rt) {
  const int i = blockIdx.x * 256 + threadIdx.x;   // < 131072
  const int s = i >> 6, j = i & 63;
  const float inv = exp2f((float)j * -0.2076205059f);
  float sn, cs;
  __sincosf((float)s * inv, &sn, &cs);
  rt[i] = make_float2(cs, sn);
}

// fp32 -> bf16 for all three inputs in one launch; dst regions contiguous.
#define N8_H  1048576
#define N8_WQ  786432
#define N8_WO  524288
__global__ __launch_bounds__(256) void cvt_all(const float* __restrict__ h,
                                               const float* __restrict__ wq,
                                               const float* __restrict__ wo,
                                               unsigned short* __restrict__ dst) {
  const int i = blockIdx.x * 256 + threadIdx.x;
  if (i >= N8_H + N8_WQ + N8_WO) return;
  const float* src; int j;
  if (i < N8_H)              { src = h;  j = i; }
  else if (i < N8_H + N8_WQ) { src = wq; j = i - N8_H; }
  else                       { src = wo; j = i - N8_H - N8_WQ; }
  const float4 a = reinterpret_cast<const float4*>(src)[j * 2];
  const float4 b = reinterpret_cast<const float4*>(src)[j * 2 + 1];
  unsigned short o[8] = {cvt1(a.x), cvt1(a.y), cvt1(a.z), cvt1(a.w),
                         cvt1(b.x), cvt1(b.y), cvt1(b.z), cvt1(b.w)};
  *reinterpret_cast<short8*>(dst + (size_t)i * 8) = *reinterpret_cast<short8*>(o);
}

// C[M,N] = A[M,K] * B[N,K]^T, bf16 in, fp32 accumulate.
// 1-D grid, XCD-aware remap: xcd=id&7 owns bn in [xcd*bng, (xcd+1)*bng) so the
// per-XCD L2 holds a small B slice (kills the 4.4x B refetch seen in R7).
// MODE 0: QKV projection + fused table-lookup RoPE epilogue -> qbuf/kbuf/vtbuf.
// MODE 1: Cout fp32 row-major.
template<int MODE>
__global__ __launch_bounds__(256) void gemm_bt(const bf16* __restrict__ A,
                                               const bf16* __restrict__ B,
                                               int M, int N, int K, int bng,
                                               const float2* __restrict__ rtab,
                                               bf16* __restrict__ qbuf,
                                               bf16* __restrict__ kbuf,
                                               bf16* __restrict__ vtbuf,
                                               float* __restrict__ Cout)
{
  __shared__ unsigned short As[128 * 32];
  __shared__ unsigned short Bs[128 * 32];
  const int id   = blockIdx.x;
  const int xcd  = id & 7, jj = id >> 3;
  const int bn   = xcd * bng + (jj % bng);
  const int bm   = jj / bng;
  const int t    = threadIdx.x;
  const int w    = t >> 6;
  const int lane = t & 63;
  const int m16  = lane & 15;
  const int quad = lane >> 4;
  const int wm   = (w >> 1) * 64;
  const int wn   = (w & 1) * 64;

  int bcol[4];
#pragma unroll
  for (int ni = 0; ni < 4; ++ni)
    bcol[ni] = (MODE == 0) ? ((w & 1) * 32 + (ni & 1) * 16 + (ni >> 1) * 64)
                           : (wn + ni * 16);

  const floatx4 zf = {0.f, 0.f, 0.f, 0.f};
  floatx4 acc[4][4];
#pragma unroll
  for (int i = 0; i < 4; ++i)
#pragma unroll
    for (int j = 0; j < 4; ++j) acc[i][j] = zf;

  const bf16* gA = A + (size_t)(bm * 128 + (t >> 2)) * K + (t & 3) * 8;
  const bf16* gB = B + (size_t)(bn * 128 + (t >> 2)) * K + (t & 3) * 8;
  unsigned short* lA = &As[w * 512];
  unsigned short* lB = &Bs[w * 512];

  for (int k0 = 0; k0 < K; k0 += 32) {
    __syncthreads();
#pragma unroll
    for (int i = 0; i < 2; ++i) {
      async_copy16(gA + (size_t)(64 * i) * K + k0, lA + i * 2048);
      async_copy16(gB + (size_t)(64 * i) * K + k0, lB + i * 2048);
    }
    __builtin_amdgcn_s_waitcnt(0);
    __syncthreads();
    short8 af[4], bfr[4];
#pragma unroll
    for (int mi = 0; mi < 4; ++mi)
      af[mi] = *reinterpret_cast<const short8*>(&As[(wm + mi * 16 + m16) * 32 + quad * 8]);
#pragma unroll
    for (int ni = 0; ni < 4; ++ni)
      bfr[ni] = *reinterpret_cast<const short8*>(&Bs[(bcol[ni] + m16) * 32 + quad * 8]);
#pragma unroll
    for (int mi = 0; mi < 4; ++mi)
#pragma unroll
      for (int ni = 0; ni < 4; ++ni)
        acc[mi][ni] = __builtin_amdgcn_mfma_f32_16x16x32_bf16(af[mi], bfr[ni], acc[mi][ni], 0, 0, 0);
  }

  if (MODE == 1) {
#pragma unroll
    for (int mi = 0; mi < 4; ++mi)
#pragma unroll
      for (int ni = 0; ni < 4; ++ni) {
        const int row0 = bm * 128 + wm + mi * 16 + quad * 4;
        const int col  = bn * 128 + bcol[ni] + m16;
#pragma unroll
        for (int r = 0; r < 4; ++r)
          Cout[(size_t)(row0 + r) * N + col] = acc[mi][ni][r];
      }
    return;
  }

  // ---- MODE 0 epilogue ----
  const int colbase = bn * 128;
  if (colbase < HIDDEN + NKVH * HDIM) {
    const bool isQ = (colbase < HIDDEN);
    const float post = isQ ? 0.08838834764831845f : 1.0f;
    const int jbase = (w & 1) * 32 + m16;
#pragma unroll
    for (int mi = 0; mi < 4; ++mi) {
      const int row0 = bm * 128 + wm + mi * 16 + quad * 4;
#pragma unroll
      for (int r = 0; r < 4; ++r) {
        const int m = row0 + r;
        const int b = m >> 11, s = m & 2047;
        const float2 t0 = rtab[(s << 6) + jbase];
        const float2 t1 = rtab[(s << 6) + jbase + 16];
        const float csv[2] = {t0.x, t1.x};
        const float snv[2] = {t0.y, t1.y};
#pragma unroll
        for (int ni = 0; ni < 4; ++ni) {
          const int p = ni & 1;
          const float v  = acc[mi][ni][r];
          const float v2 = acc[mi][ni ^ 2][r];
          const float rot = ((ni < 2) ? (v * csv[p] - v2 * snv[p])
                                      : (v * csv[p] + v2 * snv[p])) * post;
          const int col = colbase + bcol[ni] + m16;
          if (isQ) {
            const int hh = col >> 7, d = col & 127;
            qbuf[(((size_t)(b * NHEADS + hh)) * S_LEN + s) * HDIM + d] = __float2bfloat16(rot);
          } else {
            const int nn = col - HIDDEN; const int hh = nn >> 7, d = nn & 127;
            kbuf[(((size_t)(b * NKVH + hh)) * S_LEN + s) * HDIM + d] = __float2bfloat16(rot);
          }
        }
      }
    }
  } else {
#pragma unroll
    for (int mi = 0; mi < 4; ++mi)
#pragma unroll
      for (int ni = 0; ni < 4; ++ni) {
        const int row0 = bm * 128 + wm + mi * 16 + quad * 4;
        const int col  = colbase + bcol[ni] + m16;
        const int nn = col - HIDDEN - NKVH * HDIM;
        const int hh = nn >> 7, d = nn & 127;
#pragma unroll
        for (int r = 0; r < 4; ++r) {
          const int m = row0 + r;
          const int b = m >> 11, s = m & 2047;
          vtbuf[(((size_t)(b * NKVH + hh)) * HDIM + d) * S_LEN + s] =
              __float2bfloat16(acc[mi][ni][r]);
        }
      }
  }
}

// ---------------- Attention phase A: split-K partials, max-free softmax ------
// Balanced chunks (<=27 iters), descending dispatch. nch==1 tiles are final:
// divide by row-sum and write abuf directly (skip partial round-trip).
__global__ __launch_bounds__(256) void attn_partial(const bf16* __restrict__ qbuf,
                                                    const bf16* __restrict__ kbuf,
                                                    const bf16* __restrict__ vtbuf,
                                                    unsigned short* __restrict__ pnum,
                                                    float* __restrict__ plsum,
                                                    bf16* __restrict__ abuf)
{
  __shared__ unsigned short Ks[2][4096];
  __shared__ unsigned short Vs[2][4096];
  __shared__ unsigned short Ps[4][1280];
  const int sidx = 110 - blockIdx.x;       // descending dispatch
  int i2, c, nch;
  if (sidx < 27)      { i2 = sidx;                     c = 0;              nch = 1; }
  else if (sidx < 81) { i2 = 27 + ((sidx - 27) >> 1);  c = (sidx - 27) & 1; nch = 2; }
  else                { i2 = 54 + (sidx - 81) / 3;     c = (sidx - 81) % 3; nch = 3; }
  const int len = i2 + 1;
  const int k0 = (c * len) / nch, k1 = ((c + 1) * len) / nch;
  const int kvh = blockIdx.y, b = blockIdx.z;
  const int t = threadIdx.x, w = t >> 6, lane = t & 63;
  const int m16 = lane & 15, quad = lane >> 4;
  const int h = kvh * 4 + w;

  const bf16* Qp = qbuf + (((size_t)(b * NHEADS + h)) * S_LEN + i2 * 32 + m16) * HDIM;
  short8 qf[2][4];
#pragma unroll
  for (int T = 0; T < 2; ++T)
#pragma unroll
    for (int cc = 0; cc < 4; ++cc)
      qf[T][cc] = *reinterpret_cast<const short8*>(Qp + (size_t)T * 16 * HDIM + cc * 32 + quad * 8);

  const bf16* Kp  = kbuf  + ((size_t)(b * NKVH + kvh)) * S_LEN * HDIM;
  const bf16* Vtp = vtbuf + ((size_t)(b * NKVH + kvh)) * HDIM * S_LEN;

  const int kk = lane >> 4, cK = lane & 15;
  const int rKa = w * 8 + kk, rKb = rKa + 4;
  const int offKa = rKa * 128 + ((cK ^ (rKa & 7)) * 8);
  const int offKb = rKb * 128 + ((cK ^ (rKb & 7)) * 8);
  const int dd = lane >> 2, cV = lane & 3;
  const int dVa = w * 32 + dd, dVb = dVa + 16;
  const int offVa = dVa * 2048 + ((cV ^ ((dVa >> 1) & 3)) * 8);
  const int offVb = dVb * 2048 + ((cV ^ ((dVb >> 1) & 3)) * 8);

  const floatx4 zf = {0.f, 0.f, 0.f, 0.f};
  floatx4 oacc[2][8];
#pragma unroll
  for (int T = 0; T < 2; ++T)
#pragma unroll
    for (int d = 0; d < 8; ++d) oacc[T][d] = zf;
  floatx4 lacc[2] = {zf, zf};
  unsigned short ones_s[8] = {0x3F80,0x3F80,0x3F80,0x3F80,0x3F80,0x3F80,0x3F80,0x3F80};
  const short8 ones = *reinterpret_cast<short8*>(ones_s);

  unsigned short* Pw = &Ps[w][0];

  {
    const int ks = k0 * 32;
    async_copy16(Kp + (size_t)ks * 128 + offKa, &Ks[0][w * 1024]);
    async_copy16(Kp + (size_t)ks * 128 + offKb, &Ks[0][w * 1024 + 512]);
    async_copy16(Vtp + ks + offVa, &Vs[0][w * 1024]);
    async_copy16(Vtp + ks + offVb, &Vs[0][w * 1024 + 512]);
  }
  __syncthreads();

  for (int ki = k0; ki < k1; ++ki) {
    const int buf = (ki - k0) & 1;
    if (ki + 1 < k1) {
      const int ks = (ki + 1) * 32;
      async_copy16(Kp + (size_t)ks * 128 + offKa, &Ks[buf ^ 1][w * 1024]);
      async_copy16(Kp + (size_t)ks * 128 + offKb, &Ks[buf ^ 1][w * 1024 + 512]);
      async_copy16(Vtp + ks + offVa, &Vs[buf ^ 1][w * 1024]);
      async_copy16(Vtp + ks + offVb, &Vs[buf ^ 1][w * 1024 + 512]);
    }
    const int ks = ki * 32;
    floatx4 s00 = zf, s01 = zf, s10 = zf, s11 = zf;
#pragma unroll
    for (int cc = 0; cc < 4; ++cc) {
      const int sw = ((cc * 4 + quad) ^ (m16 & 7)) * 8;
      short8 kf0 = *reinterpret_cast<const short8*>(&Ks[buf][m16 * 128 + sw]);
      short8 kf1 = *reinterpret_cast<const short8*>(&Ks[buf][(16 + m16) * 128 + sw]);
      s00 = __builtin_amdgcn_mfma_f32_16x16x32_bf16(qf[0][cc], kf0, s00, 0, 0, 0);
      s01 = __builtin_amdgcn_mfma_f32_16x16x32_bf16(qf[0][cc], kf1, s01, 0, 0, 0);
      s10 = __builtin_amdgcn_mfma_f32_16x16x32_bf16(qf[1][cc], kf0, s10, 0, 0, 0);
      s11 = __builtin_amdgcn_mfma_f32_16x16x32_bf16(qf[1][cc], kf1, s11, 0, 0, 0);
    }
#pragma unroll
    for (int T = 0; T < 2; ++T) {
      const floatx4& sa = T ? s10 : s00;
      const floatx4& sb = T ? s11 : s01;
#pragma unroll
      for (int r = 0; r < 4; ++r) {
        const int row = i2 * 32 + T * 16 + quad * 4 + r;
        const float p0 = (ks + m16      > row) ? 0.f : __expf(sa[r]);
        const float p1 = (ks + 16 + m16 > row) ? 0.f : __expf(sb[r]);
        Pw[(T * 16 + quad * 4 + r) * 40 + m16]      = cvt1(p0);
        Pw[(T * 16 + quad * 4 + r) * 40 + 16 + m16] = cvt1(p1);
      }
    }
    const short8 pa0 = *reinterpret_cast<const short8*>(&Pw[m16 * 40 + quad * 8]);
    const short8 pa1 = *reinterpret_cast<const short8*>(&Pw[(16 + m16) * 40 + quad * 8]);
    lacc[0] = __builtin_amdgcn_mfma_f32_16x16x32_bf16(pa0, ones, lacc[0], 0, 0, 0);
    lacc[1] = __builtin_amdgcn_mfma_f32_16x16x32_bf16(pa1, ones, lacc[1], 0, 0, 0);
#pragma unroll
    for (int dt = 0; dt < 8; ++dt) {
      short8 vfr = *reinterpret_cast<const short8*>(
          &Vs[buf][(dt * 16 + m16) * 32 + ((quad ^ ((m16 >> 1) & 3)) * 8)]);
      oacc[0][dt] = __builtin_amdgcn_mfma_f32_16x16x32_bf16(pa0, vfr, oacc[0][dt], 0, 0, 0);
      oacc[1][dt] = __builtin_amdgcn_mfma_f32_16x16x32_bf16(pa1, vfr, oacc[1][dt], 0, 0, 0);
    }
    __syncthreads();
  }

  if (nch == 1) {
    // final: divide by row-sum, write abuf directly
#pragma unroll
    for (int T = 0; T < 2; ++T) {
      float invl[4];
#pragma unroll
      for (int r = 0; r < 4; ++r) invl[r] = 1.0f / lacc[T][r];
      bf16* op = abuf + (((size_t)b * S_LEN + i2 * 32 + T * 16 + quad * 4) * NHEADS + h) * HDIM + m16;
#pragma unroll
      for (int dt = 0; dt < 8; ++dt)
#pragma unroll
        for (int r = 0; r < 4; ++r)
          op[(size_t)r * NHEADS * HDIM + dt * 16] = __float2bfloat16(oacc[T][dt][r] * invl[r]);
    }
  } else {
    const int b0 = (i2 < 54) ? (27 + 2 * (i2 - 27)) : (81 + 3 * (i2 - 54));
    const int slot = (b * NHEADS + h) * 111 + b0 + c;
    unsigned short* np = pnum + (size_t)slot * 4096;
#pragma unroll
    for (int T = 0; T < 2; ++T)
#pragma unroll
      for (int dt = 0; dt < 8; ++dt)
#pragma unroll
        for (int r = 0; r < 4; ++r)
          np[(T * 16 + quad * 4 + r) * 128 + dt * 16 + m16] = cvt1(oacc[T][dt][r]);
    if (m16 == 0) {
#pragma unroll
      for (int T = 0; T < 2; ++T)
#pragma unroll
        for (int r = 0; r < 4; ++r)
          plsum[slot * 32 + T * 16 + quad * 4 + r] = lacc[T][r];
    }
  }
}

// ---------------- Attention phase B: combine multi-chunk tiles only ----------
__global__ __launch_bounds__(256) void attn_combine(const unsigned short* __restrict__ pnum,
                                                    const float* __restrict__ plsum,
                                                    bf16* __restrict__ abuf)
{
  const int i = 54 + blockIdx.x;                     // 16-row tiles 54..127
  const int h = blockIdx.y, b = blockIdx.z;
  const int i2 = i >> 1, lr0 = (i & 1) * 16;
  const int t = threadIdx.x, row16 = t >> 4, c0 = (t & 15) * 8;
  const int lr = lr0 + row16;
  const int nch = (i2 < 54) ? 2 : 3;
  const int b0  = (i2 < 54) ? (27 + 2 * (i2 - 27)) : (81 + 3 * (i2 - 54));
  const int hb = (b * NHEADS + h) * 111 + b0;
  float acc[8] = {0.f,0.f,0.f,0.f,0.f,0.f,0.f,0.f};
  float lsum = 0.f;
  for (int c = 0; c < nch; ++c) {
    const unsigned short* np = pnum + (size_t)(hb + c) * 4096 + lr * 128 + c0;
    const short8 v = *reinterpret_cast<const short8*>(np);
#pragma unroll
    for (int j = 0; j < 8; ++j) acc[j] += us2f(((unsigned short*)&v)[j]);
    lsum += plsum[(hb + c) * 32 + lr];
  }
  const float invl = 1.0f / lsum;
  unsigned short o[8];
#pragma unroll
  for (int j = 0; j < 8; ++j) o[j] = cvt1(acc[j] * invl);
  *reinterpret_cast<short8*>(abuf + (((size_t)b * S_LEN + i * 16 + row16) * NHEADS + h) * HDIM + c0)
      = *reinterpret_cast<short8*>(o);
}

extern "C" void kernel_launch(void* const* d_in, const int* in_sizes, int n_in,
                              void* d_out, int out_size, void* d_ws, size_t ws_size,
                              hipStream_t stream) {
  const float* hidden_f = (const float*)d_in[0];
  const float* wqkv_f   = (const float*)d_in[1];
  const float* wout_f   = (const float*)d_in[2];
  float* out = (float*)d_out;

  char* ws = (char*)d_ws;
  bf16* hbf    = (bf16*)(ws);                    // [4096,2048]   (dead after gemm0)
  bf16* wqkvbf = (bf16*)(ws + 16777216);         // [3072,2048]   (dead after gemm0)
  bf16* woutbf = (bf16*)(ws + 29360128);         // [2048,2048]
  bf16* qbuf   = (bf16*)(ws + 37748736);         // [B,NH,S,HD]
  bf16* kbuf   = (bf16*)(ws + 54525952);         // [B,NKV,S,HD]
  bf16* vtbuf  = (bf16*)(ws + 58720256);         // [B,NKV,HD,S]
  bf16* abuf   = (bf16*)(ws + 62914560);         // [B,S,NH,HD]
  unsigned short* pnum = (unsigned short*)(ws);  // overlay: 3552 x 8KB = 29.1 MB
  float* plsum = (float*)(ws + 79691776);        // 3552 x 32 fp32 (0.45 MB)
  float2* rtab = (float2*)(ws + 81788928);       // 2048 x 64 float2 (1 MB)

  rope_table<<<512, 256, 0, stream>>>(rtab);
  cvt_all<<<9216, 256, 0, stream>>>(hidden_f, wqkv_f, wout_f, (unsigned short*)ws);

  gemm_bt<0><<<768, 256, 0, stream>>>(hbf, wqkvbf, 4096, 3072, 2048, 3, rtab,
                                      qbuf, kbuf, vtbuf, nullptr);
  attn_partial<<<dim3(111, 4, 2), 256, 0, stream>>>(qbuf, kbuf, vtbuf, pnum, plsum, abuf);
  attn_combine<<<dim3(74, 16, 2), 256, 0, stream>>>(pnum, plsum, abuf);
  gemm_bt<1><<<512, 256, 0, stream>>>(abuf, woutbf, 4096, 2048, 2048, 2, nullptr,
                                      nullptr, nullptr, nullptr, out);
}

// Round 9
// 366.834 us; speedup vs baseline: 1.0026x; 1.0026x over previous
//
#include <hip/hip_runtime.h>
#include <hip/hip_bf16.h>
#include <math.h>

#define S_LEN   2048
#define HIDDEN  2048
#define NHEADS  16
#define NKVH    4
#define HDIM    128

typedef short  short8  __attribute__((ext_vector_type(8)));
typedef float  floatx4 __attribute__((ext_vector_type(4)));
typedef __hip_bfloat16 bf16;

__device__ inline void async_copy16(const void* g, void* l) {
  __builtin_amdgcn_global_load_lds((__attribute__((address_space(1))) void*)(g),
                                   (__attribute__((address_space(3))) void*)(l),
                                   16, 0, 0);
}

__device__ inline unsigned short cvt1(float x) {
  bf16 t = __float2bfloat16(x);
  return *reinterpret_cast<unsigned short*>(&t);
}
__device__ inline float us2f(unsigned short u) {
  unsigned int v = ((unsigned int)u) << 16;
  return *reinterpret_cast<float*>(&v);
}

// RoPE table: rt[s*64 + j] = (cos, sin)(s * 10000^(-j/64))
__global__ __launch_bounds__(256) void rope_table(float2* __restrict__ rt) {
  const int i = blockIdx.x * 256 + threadIdx.x;   // < 131072
  const int s = i >> 6, j = i & 63;
  const float inv = exp2f((float)j * -0.2076205059f);
  float sn, cs;
  __sincosf((float)s * inv, &sn, &cs);
  rt[i] = make_float2(cs, sn);
}

// fp32 -> bf16 for all three inputs in one launch; dst regions contiguous.
#define N8_H  1048576
#define N8_WQ  786432
#define N8_WO  524288
__global__ __launch_bounds__(256) void cvt_all(const float* __restrict__ h,
                                               const float* __restrict__ wq,
                                               const float* __restrict__ wo,
                                               unsigned short* __restrict__ dst) {
  const int i = blockIdx.x * 256 + threadIdx.x;
  if (i >= N8_H + N8_WQ + N8_WO) return;
  const float* src; int j;
  if (i < N8_H)              { src = h;  j = i; }
  else if (i < N8_H + N8_WQ) { src = wq; j = i - N8_H; }
  else                       { src = wo; j = i - N8_H - N8_WQ; }
  const float4 a = reinterpret_cast<const float4*>(src)[j * 2];
  const float4 b = reinterpret_cast<const float4*>(src)[j * 2 + 1];
  unsigned short o[8] = {cvt1(a.x), cvt1(a.y), cvt1(a.z), cvt1(a.w),
                         cvt1(b.x), cvt1(b.y), cvt1(b.z), cvt1(b.w)};
  *reinterpret_cast<short8*>(dst + (size_t)i * 8) = *reinterpret_cast<short8*>(o);
}

// C[M,N] = A[M,K] * B[N,K]^T, bf16 in, fp32 accumulate.
// 2-D grid (bn = blockIdx.x fast): natural dispatch order already gives each
// XCD a fixed B-slice (bn % 8) AND same-bm A-tile sharing — R8's explicit
// remap broke this and regressed 35%; do not re-introduce it.
// MODE 0: QKV projection + fused table-lookup RoPE epilogue -> qbuf/kbuf/vtbuf.
// MODE 1: Cout fp32 row-major.
template<int MODE>
__global__ __launch_bounds__(256) void gemm_bt(const bf16* __restrict__ A,
                                               const bf16* __restrict__ B,
                                               int M, int N, int K,
                                               const float2* __restrict__ rtab,
                                               bf16* __restrict__ qbuf,
                                               bf16* __restrict__ kbuf,
                                               bf16* __restrict__ vtbuf,
                                               float* __restrict__ Cout)
{
  __shared__ unsigned short As[128 * 32];
  __shared__ unsigned short Bs[128 * 32];
  const int bn   = blockIdx.x;
  const int bm   = blockIdx.y;
  const int t    = threadIdx.x;
  const int w    = t >> 6;
  const int lane = t & 63;
  const int m16  = lane & 15;
  const int quad = lane >> 4;
  const int wm   = (w >> 1) * 64;
  const int wn   = (w & 1) * 64;

  int bcol[4];
#pragma unroll
  for (int ni = 0; ni < 4; ++ni)
    bcol[ni] = (MODE == 0) ? ((w & 1) * 32 + (ni & 1) * 16 + (ni >> 1) * 64)
                           : (wn + ni * 16);

  const floatx4 zf = {0.f, 0.f, 0.f, 0.f};
  floatx4 acc[4][4];
#pragma unroll
  for (int i = 0; i < 4; ++i)
#pragma unroll
    for (int j = 0; j < 4; ++j) acc[i][j] = zf;

  const bf16* gA = A + (size_t)(bm * 128 + (t >> 2)) * K + (t & 3) * 8;
  const bf16* gB = B + (size_t)(bn * 128 + (t >> 2)) * K + (t & 3) * 8;
  unsigned short* lA = &As[w * 512];
  unsigned short* lB = &Bs[w * 512];

  for (int k0 = 0; k0 < K; k0 += 32) {
    __syncthreads();
#pragma unroll
    for (int i = 0; i < 2; ++i) {
      async_copy16(gA + (size_t)(64 * i) * K + k0, lA + i * 2048);
      async_copy16(gB + (size_t)(64 * i) * K + k0, lB + i * 2048);
    }
    __builtin_amdgcn_s_waitcnt(0);
    __syncthreads();
    short8 af[4], bfr[4];
#pragma unroll
    for (int mi = 0; mi < 4; ++mi)
      af[mi] = *reinterpret_cast<const short8*>(&As[(wm + mi * 16 + m16) * 32 + quad * 8]);
#pragma unroll
    for (int ni = 0; ni < 4; ++ni)
      bfr[ni] = *reinterpret_cast<const short8*>(&Bs[(bcol[ni] + m16) * 32 + quad * 8]);
#pragma unroll
    for (int mi = 0; mi < 4; ++mi)
#pragma unroll
      for (int ni = 0; ni < 4; ++ni)
        acc[mi][ni] = __builtin_amdgcn_mfma_f32_16x16x32_bf16(af[mi], bfr[ni], acc[mi][ni], 0, 0, 0);
  }

  if (MODE == 1) {
#pragma unroll
    for (int mi = 0; mi < 4; ++mi)
#pragma unroll
      for (int ni = 0; ni < 4; ++ni) {
        const int row0 = bm * 128 + wm + mi * 16 + quad * 4;
        const int col  = bn * 128 + bcol[ni] + m16;
#pragma unroll
        for (int r = 0; r < 4; ++r)
          Cout[(size_t)(row0 + r) * N + col] = acc[mi][ni][r];
      }
    return;
  }

  // ---- MODE 0 epilogue ----
  const int colbase = bn * 128;
  if (colbase < HIDDEN + NKVH * HDIM) {
    const bool isQ = (colbase < HIDDEN);
    const float post = isQ ? 0.08838834764831845f : 1.0f;
    const int jbase = (w & 1) * 32 + m16;
#pragma unroll
    for (int mi = 0; mi < 4; ++mi) {
      const int row0 = bm * 128 + wm + mi * 16 + quad * 4;
#pragma unroll
      for (int r = 0; r < 4; ++r) {
        const int m = row0 + r;
        const int b = m >> 11, s = m & 2047;
        const float2 t0 = rtab[(s << 6) + jbase];
        const float2 t1 = rtab[(s << 6) + jbase + 16];
        const float csv[2] = {t0.x, t1.x};
        const float snv[2] = {t0.y, t1.y};
#pragma unroll
        for (int ni = 0; ni < 4; ++ni) {
          const int p = ni & 1;
          const float v  = acc[mi][ni][r];
          const float v2 = acc[mi][ni ^ 2][r];
          const float rot = ((ni < 2) ? (v * csv[p] - v2 * snv[p])
                                      : (v * csv[p] + v2 * snv[p])) * post;
          const int col = colbase + bcol[ni] + m16;
          if (isQ) {
            const int hh = col >> 7, d = col & 127;
            qbuf[(((size_t)(b * NHEADS + hh)) * S_LEN + s) * HDIM + d] = __float2bfloat16(rot);
          } else {
            const int nn = col - HIDDEN; const int hh = nn >> 7, d = nn & 127;
            kbuf[(((size_t)(b * NKVH + hh)) * S_LEN + s) * HDIM + d] = __float2bfloat16(rot);
          }
        }
      }
    }
  } else {
#pragma unroll
    for (int mi = 0; mi < 4; ++mi)
#pragma unroll
      for (int ni = 0; ni < 4; ++ni) {
        const int row0 = bm * 128 + wm + mi * 16 + quad * 4;
        const int col  = colbase + bcol[ni] + m16;
        const int nn = col - HIDDEN - NKVH * HDIM;
        const int hh = nn >> 7, d = nn & 127;
#pragma unroll
        for (int r = 0; r < 4; ++r) {
          const int m = row0 + r;
          const int b = m >> 11, s = m & 2047;
          vtbuf[(((size_t)(b * NKVH + hh)) * HDIM + d) * S_LEN + s] =
              __float2bfloat16(acc[mi][ni][r]);
        }
      }
  }
}

// ---------------- Attention phase A: split-K partials, max-free softmax ------
// Balanced chunks (<=27 iters), descending dispatch. nch==1 tiles are final:
// divide by row-sum and write abuf directly (skip partial round-trip).
__global__ __launch_bounds__(256) void attn_partial(const bf16* __restrict__ qbuf,
                                                    const bf16* __restrict__ kbuf,
                                                    const bf16* __restrict__ vtbuf,
                                                    unsigned short* __restrict__ pnum,
                                                    float* __restrict__ plsum,
                                                    bf16* __restrict__ abuf)
{
  __shared__ unsigned short Ks[2][4096];
  __shared__ unsigned short Vs[2][4096];
  __shared__ unsigned short Ps[4][1280];
  const int sidx = 110 - blockIdx.x;       // descending dispatch
  int i2, c, nch;
  if (sidx < 27)      { i2 = sidx;                     c = 0;              nch = 1; }
  else if (sidx < 81) { i2 = 27 + ((sidx - 27) >> 1);  c = (sidx - 27) & 1; nch = 2; }
  else                { i2 = 54 + (sidx - 81) / 3;     c = (sidx - 81) % 3; nch = 3; }
  const int len = i2 + 1;
  const int k0 = (c * len) / nch, k1 = ((c + 1) * len) / nch;
  const int kvh = blockIdx.y, b = blockIdx.z;
  const int t = threadIdx.x, w = t >> 6, lane = t & 63;
  const int m16 = lane & 15, quad = lane >> 4;
  const int h = kvh * 4 + w;

  const bf16* Qp = qbuf + (((size_t)(b * NHEADS + h)) * S_LEN + i2 * 32 + m16) * HDIM;
  short8 qf[2][4];
#pragma unroll
  for (int T = 0; T < 2; ++T)
#pragma unroll
    for (int cc = 0; cc < 4; ++cc)
      qf[T][cc] = *reinterpret_cast<const short8*>(Qp + (size_t)T * 16 * HDIM + cc * 32 + quad * 8);

  const bf16* Kp  = kbuf  + ((size_t)(b * NKVH + kvh)) * S_LEN * HDIM;
  const bf16* Vtp = vtbuf + ((size_t)(b * NKVH + kvh)) * HDIM * S_LEN;

  const int kk = lane >> 4, cK = lane & 15;
  const int rKa = w * 8 + kk, rKb = rKa + 4;
  const int offKa = rKa * 128 + ((cK ^ (rKa & 7)) * 8);
  const int offKb = rKb * 128 + ((cK ^ (rKb & 7)) * 8);
  const int dd = lane >> 2, cV = lane & 3;
  const int dVa = w * 32 + dd, dVb = dVa + 16;
  const int offVa = dVa * 2048 + ((cV ^ ((dVa >> 1) & 3)) * 8);
  const int offVb = dVb * 2048 + ((cV ^ ((dVb >> 1) & 3)) * 8);

  const floatx4 zf = {0.f, 0.f, 0.f, 0.f};
  floatx4 oacc[2][8];
#pragma unroll
  for (int T = 0; T < 2; ++T)
#pragma unroll
    for (int d = 0; d < 8; ++d) oacc[T][d] = zf;
  floatx4 lacc[2] = {zf, zf};
  unsigned short ones_s[8] = {0x3F80,0x3F80,0x3F80,0x3F80,0x3F80,0x3F80,0x3F80,0x3F80};
  const short8 ones = *reinterpret_cast<short8*>(ones_s);

  unsigned short* Pw = &Ps[w][0];

  {
    const int ks = k0 * 32;
    async_copy16(Kp + (size_t)ks * 128 + offKa, &Ks[0][w * 1024]);
    async_copy16(Kp + (size_t)ks * 128 + offKb, &Ks[0][w * 1024 + 512]);
    async_copy16(Vtp + ks + offVa, &Vs[0][w * 1024]);
    async_copy16(Vtp + ks + offVb, &Vs[0][w * 1024 + 512]);
  }
  __syncthreads();

  for (int ki = k0; ki < k1; ++ki) {
    const int buf = (ki - k0) & 1;
    if (ki + 1 < k1) {
      const int ks = (ki + 1) * 32;
      async_copy16(Kp + (size_t)ks * 128 + offKa, &Ks[buf ^ 1][w * 1024]);
      async_copy16(Kp + (size_t)ks * 128 + offKb, &Ks[buf ^ 1][w * 1024 + 512]);
      async_copy16(Vtp + ks + offVa, &Vs[buf ^ 1][w * 1024]);
      async_copy16(Vtp + ks + offVb, &Vs[buf ^ 1][w * 1024 + 512]);
    }
    const int ks = ki * 32;
    floatx4 s00 = zf, s01 = zf, s10 = zf, s11 = zf;
#pragma unroll
    for (int cc = 0; cc < 4; ++cc) {
      const int sw = ((cc * 4 + quad) ^ (m16 & 7)) * 8;
      short8 kf0 = *reinterpret_cast<const short8*>(&Ks[buf][m16 * 128 + sw]);
      short8 kf1 = *reinterpret_cast<const short8*>(&Ks[buf][(16 + m16) * 128 + sw]);
      s00 = __builtin_amdgcn_mfma_f32_16x16x32_bf16(qf[0][cc], kf0, s00, 0, 0, 0);
      s01 = __builtin_amdgcn_mfma_f32_16x16x32_bf16(qf[0][cc], kf1, s01, 0, 0, 0);
      s10 = __builtin_amdgcn_mfma_f32_16x16x32_bf16(qf[1][cc], kf0, s10, 0, 0, 0);
      s11 = __builtin_amdgcn_mfma_f32_16x16x32_bf16(qf[1][cc], kf1, s11, 0, 0, 0);
    }
#pragma unroll
    for (int T = 0; T < 2; ++T) {
      const floatx4& sa = T ? s10 : s00;
      const floatx4& sb = T ? s11 : s01;
#pragma unroll
      for (int r = 0; r < 4; ++r) {
        const int row = i2 * 32 + T * 16 + quad * 4 + r;
        const float p0 = (ks + m16      > row) ? 0.f : __expf(sa[r]);
        const float p1 = (ks + 16 + m16 > row) ? 0.f : __expf(sb[r]);
        Pw[(T * 16 + quad * 4 + r) * 40 + m16]      = cvt1(p0);
        Pw[(T * 16 + quad * 4 + r) * 40 + 16 + m16] = cvt1(p1);
      }
    }
    const short8 pa0 = *reinterpret_cast<const short8*>(&Pw[m16 * 40 + quad * 8]);
    const short8 pa1 = *reinterpret_cast<const short8*>(&Pw[(16 + m16) * 40 + quad * 8]);
    lacc[0] = __builtin_amdgcn_mfma_f32_16x16x32_bf16(pa0, ones, lacc[0], 0, 0, 0);
    lacc[1] = __builtin_amdgcn_mfma_f32_16x16x32_bf16(pa1, ones, lacc[1], 0, 0, 0);
#pragma unroll
    for (int dt = 0; dt < 8; ++dt) {
      short8 vfr = *reinterpret_cast<const short8*>(
          &Vs[buf][(dt * 16 + m16) * 32 + ((quad ^ ((m16 >> 1) & 3)) * 8)]);
      oacc[0][dt] = __builtin_amdgcn_mfma_f32_16x16x32_bf16(pa0, vfr, oacc[0][dt], 0, 0, 0);
      oacc[1][dt] = __builtin_amdgcn_mfma_f32_16x16x32_bf16(pa1, vfr, oacc[1][dt], 0, 0, 0);
    }
    __syncthreads();
  }

  if (nch == 1) {
    // final: divide by row-sum, write abuf directly
#pragma unroll
    for (int T = 0; T < 2; ++T) {
      float invl[4];
#pragma unroll
      for (int r = 0; r < 4; ++r) invl[r] = 1.0f / lacc[T][r];
      bf16* op = abuf + (((size_t)b * S_LEN + i2 * 32 + T * 16 + quad * 4) * NHEADS + h) * HDIM + m16;
#pragma unroll
      for (int dt = 0; dt < 8; ++dt)
#pragma unroll
        for (int r = 0; r < 4; ++r)
          op[(size_t)r * NHEADS * HDIM + dt * 16] = __float2bfloat16(oacc[T][dt][r] * invl[r]);
    }
  } else {
    const int b0 = (i2 < 54) ? (27 + 2 * (i2 - 27)) : (81 + 3 * (i2 - 54));
    const int slot = (b * NHEADS + h) * 111 + b0 + c;
    unsigned short* np = pnum + (size_t)slot * 4096;
#pragma unroll
    for (int T = 0; T < 2; ++T)
#pragma unroll
      for (int dt = 0; dt < 8; ++dt)
#pragma unroll
        for (int r = 0; r < 4; ++r)
          np[(T * 16 + quad * 4 + r) * 128 + dt * 16 + m16] = cvt1(oacc[T][dt][r]);
    if (m16 == 0) {
#pragma unroll
      for (int T = 0; T < 2; ++T)
#pragma unroll
        for (int r = 0; r < 4; ++r)
          plsum[slot * 32 + T * 16 + quad * 4 + r] = lacc[T][r];
    }
  }
}

// ---------------- Attention phase B: combine multi-chunk tiles only ----------
__global__ __launch_bounds__(256) void attn_combine(const unsigned short* __restrict__ pnum,
                                                    const float* __restrict__ plsum,
                                                    bf16* __restrict__ abuf)
{
  const int i = 54 + blockIdx.x;                     // 16-row tiles 54..127
  const int h = blockIdx.y, b = blockIdx.z;
  const int i2 = i >> 1, lr0 = (i & 1) * 16;
  const int t = threadIdx.x, row16 = t >> 4, c0 = (t & 15) * 8;
  const int lr = lr0 + row16;
  const int nch = (i2 < 54) ? 2 : 3;
  const int b0  = (i2 < 54) ? (27 + 2 * (i2 - 27)) : (81 + 3 * (i2 - 54));
  const int hb = (b * NHEADS + h) * 111 + b0;
  float acc[8] = {0.f,0.f,0.f,0.f,0.f,0.f,0.f,0.f};
  float lsum = 0.f;
  for (int c = 0; c < nch; ++c) {
    const unsigned short* np = pnum + (size_t)(hb + c) * 4096 + lr * 128 + c0;
    const short8 v = *reinterpret_cast<const short8*>(np);
#pragma unroll
    for (int j = 0; j < 8; ++j) acc[j] += us2f(((unsigned short*)&v)[j]);
    lsum += plsum[(hb + c) * 32 + lr];
  }
  const float invl = 1.0f / lsum;
  unsigned short o[8];
#pragma unroll
  for (int j = 0; j < 8; ++j) o[j] = cvt1(acc[j] * invl);
  *reinterpret_cast<short8*>(abuf + (((size_t)b * S_LEN + i * 16 + row16) * NHEADS + h) * HDIM + c0)
      = *reinterpret_cast<short8*>(o);
}

extern "C" void kernel_launch(void* const* d_in, const int* in_sizes, int n_in,
                              void* d_out, int out_size, void* d_ws, size_t ws_size,
                              hipStream_t stream) {
  const float* hidden_f = (const float*)d_in[0];
  const float* wqkv_f   = (const float*)d_in[1];
  const float* wout_f   = (const float*)d_in[2];
  float* out = (float*)d_out;

  char* ws = (char*)d_ws;
  bf16* hbf    = (bf16*)(ws);                    // [4096,2048]   (dead after gemm0)
  bf16* wqkvbf = (bf16*)(ws + 16777216);         // [3072,2048]   (dead after gemm0)
  bf16* woutbf = (bf16*)(ws + 29360128);         // [2048,2048]
  bf16* qbuf   = (bf16*)(ws + 37748736);         // [B,NH,S,HD]
  bf16* kbuf   = (bf16*)(ws + 54525952);         // [B,NKV,S,HD]
  bf16* vtbuf  = (bf16*)(ws + 58720256);         // [B,NKV,HD,S]
  bf16* abuf   = (bf16*)(ws + 62914560);         // [B,S,NH,HD]
  unsigned short* pnum = (unsigned short*)(ws);  // overlay: 3552 x 8KB = 29.1 MB
  float* plsum = (float*)(ws + 79691776);        // 3552 x 32 fp32 (0.45 MB)
  float2* rtab = (float2*)(ws + 81788928);       // 2048 x 64 float2 (1 MB)

  rope_table<<<512, 256, 0, stream>>>(rtab);
  cvt_all<<<9216, 256, 0, stream>>>(hidden_f, wqkv_f, wout_f, (unsigned short*)ws);

  gemm_bt<0><<<dim3(24, 32), 256, 0, stream>>>(hbf, wqkvbf, 4096, 3072, 2048, rtab,
                                               qbuf, kbuf, vtbuf, nullptr);
  attn_partial<<<dim3(111, 4, 2), 256, 0, stream>>>(qbuf, kbuf, vtbuf, pnum, plsum, abuf);
  attn_combine<<<dim3(74, 16, 2), 256, 0, stream>>>(pnum, plsum, abuf);
  gemm_bt<1><<<dim3(16, 32), 256, 0, stream>>>(abuf, woutbf, 4096, 2048, 2048, nullptr,
                                               nullptr, nullptr, nullptr, out);
}

// Round 10
// 333.746 us; speedup vs baseline: 1.1020x; 1.0991x over previous
//
#include <hip/hip_runtime.h>
#include <hip/hip_bf16.h>
#include <math.h>

#define S_LEN   2048
#define HIDDEN  2048
#define NHEADS  16
#define NKVH    4
#define HDIM    128

typedef short  short8  __attribute__((ext_vector_type(8)));
typedef float  floatx4 __attribute__((ext_vector_type(4)));
typedef __hip_bfloat16 bf16;

__device__ inline void async_copy16(const void* g, void* l) {
  __builtin_amdgcn_global_load_lds((__attribute__((address_space(1))) void*)(g),
                                   (__attribute__((address_space(3))) void*)(l),
                                   16, 0, 0);
}

__device__ inline unsigned short cvt1(float x) {
  bf16 t = __float2bfloat16(x);
  return *reinterpret_cast<unsigned short*>(&t);
}
__device__ inline float us2f(unsigned short u) {
  unsigned int v = ((unsigned int)u) << 16;
  return *reinterpret_cast<float*>(&v);
}

// fp32 -> bf16 for all three inputs in one launch; dst regions contiguous.
#define N8_H  1048576
#define N8_WQ  786432
#define N8_WO  524288
__global__ __launch_bounds__(256) void cvt_all(const float* __restrict__ h,
                                               const float* __restrict__ wq,
                                               const float* __restrict__ wo,
                                               unsigned short* __restrict__ dst) {
  const int i = blockIdx.x * 256 + threadIdx.x;
  if (i >= N8_H + N8_WQ + N8_WO) return;
  const float* src; int j;
  if (i < N8_H)              { src = h;  j = i; }
  else if (i < N8_H + N8_WQ) { src = wq; j = i - N8_H; }
  else                       { src = wo; j = i - N8_H - N8_WQ; }
  const float4 a = reinterpret_cast<const float4*>(src)[j * 2];
  const float4 b = reinterpret_cast<const float4*>(src)[j * 2 + 1];
  unsigned short o[8] = {cvt1(a.x), cvt1(a.y), cvt1(a.z), cvt1(a.w),
                         cvt1(b.x), cvt1(b.y), cvt1(b.z), cvt1(b.w)};
  *reinterpret_cast<short8*>(dst + (size_t)i * 8) = *reinterpret_cast<short8*>(o);
}

// C[M,N] = A[M,K] * B[N,K]^T, bf16 in, fp32 accumulate.
// 2-D grid (bn = blockIdx.x fast): natural dispatch already gives per-XCD
// B-slices (bn % 8) + same-bm A-tile sharing. R8's explicit XCD remap was
// NEUTRAL (R9 A/B); the R8 regression was the rtab epilogue: table lookups
// added ~15 MB L2-thrash refetch + exposed load latency, while inline
// __sincosf is trans-pipe work that hides under MFMA. Keep sincos inline.
// MODE 0: QKV projection + fused in-wave RoPE epilogue -> qbuf/kbuf/vtbuf.
// MODE 1: Cout fp32 row-major.
template<int MODE>
__global__ __launch_bounds__(256) void gemm_bt(const bf16* __restrict__ A,
                                               const bf16* __restrict__ B,
                                               int M, int N, int K,
                                               bf16* __restrict__ qbuf,
                                               bf16* __restrict__ kbuf,
                                               bf16* __restrict__ vtbuf,
                                               float* __restrict__ Cout)
{
  __shared__ unsigned short As[128 * 32];
  __shared__ unsigned short Bs[128 * 32];
  const int bn   = blockIdx.x;
  const int bm   = blockIdx.y;
  const int t    = threadIdx.x;
  const int w    = t >> 6;
  const int lane = t & 63;
  const int m16  = lane & 15;
  const int quad = lane >> 4;
  const int wm   = (w >> 1) * 64;
  const int wn   = (w & 1) * 64;

  int bcol[4];
#pragma unroll
  for (int ni = 0; ni < 4; ++ni)
    bcol[ni] = (MODE == 0) ? ((w & 1) * 32 + (ni & 1) * 16 + (ni >> 1) * 64)
                           : (wn + ni * 16);

  const floatx4 zf = {0.f, 0.f, 0.f, 0.f};
  floatx4 acc[4][4];
#pragma unroll
  for (int i = 0; i < 4; ++i)
#pragma unroll
    for (int j = 0; j < 4; ++j) acc[i][j] = zf;

  const bf16* gA = A + (size_t)(bm * 128 + (t >> 2)) * K + (t & 3) * 8;
  const bf16* gB = B + (size_t)(bn * 128 + (t >> 2)) * K + (t & 3) * 8;
  unsigned short* lA = &As[w * 512];
  unsigned short* lB = &Bs[w * 512];

  for (int k0 = 0; k0 < K; k0 += 32) {
    __syncthreads();
#pragma unroll
    for (int i = 0; i < 2; ++i) {
      async_copy16(gA + (size_t)(64 * i) * K + k0, lA + i * 2048);
      async_copy16(gB + (size_t)(64 * i) * K + k0, lB + i * 2048);
    }
    __builtin_amdgcn_s_waitcnt(0);
    __syncthreads();
    short8 af[4], bfr[4];
#pragma unroll
    for (int mi = 0; mi < 4; ++mi)
      af[mi] = *reinterpret_cast<const short8*>(&As[(wm + mi * 16 + m16) * 32 + quad * 8]);
#pragma unroll
    for (int ni = 0; ni < 4; ++ni)
      bfr[ni] = *reinterpret_cast<const short8*>(&Bs[(bcol[ni] + m16) * 32 + quad * 8]);
#pragma unroll
    for (int mi = 0; mi < 4; ++mi)
#pragma unroll
      for (int ni = 0; ni < 4; ++ni)
        acc[mi][ni] = __builtin_amdgcn_mfma_f32_16x16x32_bf16(af[mi], bfr[ni], acc[mi][ni], 0, 0, 0);
  }

  if (MODE == 1) {
#pragma unroll
    for (int mi = 0; mi < 4; ++mi)
#pragma unroll
      for (int ni = 0; ni < 4; ++ni) {
        const int row0 = bm * 128 + wm + mi * 16 + quad * 4;
        const int col  = bn * 128 + bcol[ni] + m16;
#pragma unroll
        for (int r = 0; r < 4; ++r)
          Cout[(size_t)(row0 + r) * N + col] = acc[mi][ni][r];
      }
    return;
  }

  // ---- MODE 0 epilogue: in-wave RoPE with inline sincos ----
  const int colbase = bn * 128;
  if (colbase < HIDDEN + NKVH * HDIM) {
    const bool isQ = (colbase < HIDDEN);
    const float post = isQ ? 0.08838834764831845f : 1.0f;
    float invf[2];
#pragma unroll
    for (int p = 0; p < 2; ++p)
      invf[p] = exp2f((float)((w & 1) * 32 + p * 16 + m16) * -0.2076205059f);
#pragma unroll
    for (int mi = 0; mi < 4; ++mi) {
      const int row0 = bm * 128 + wm + mi * 16 + quad * 4;
#pragma unroll
      for (int r = 0; r < 4; ++r) {
        const int m = row0 + r;
        const int b = m >> 11, s = m & 2047;
        float sn[2], cs[2];
        __sincosf((float)s * invf[0], &sn[0], &cs[0]);
        __sincosf((float)s * invf[1], &sn[1], &cs[1]);
#pragma unroll
        for (int ni = 0; ni < 4; ++ni) {
          const int p = ni & 1;
          const float v  = acc[mi][ni][r];
          const float v2 = acc[mi][ni ^ 2][r];
          const float rot = ((ni < 2) ? (v * cs[p] - v2 * sn[p])
                                      : (v * cs[p] + v2 * sn[p])) * post;
          const int col = colbase + bcol[ni] + m16;
          if (isQ) {
            const int hh = col >> 7, d = col & 127;
            qbuf[(((size_t)(b * NHEADS + hh)) * S_LEN + s) * HDIM + d] = __float2bfloat16(rot);
          } else {
            const int nn = col - HIDDEN; const int hh = nn >> 7, d = nn & 127;
            kbuf[(((size_t)(b * NKVH + hh)) * S_LEN + s) * HDIM + d] = __float2bfloat16(rot);
          }
        }
      }
    }
  } else {
#pragma unroll
    for (int mi = 0; mi < 4; ++mi)
#pragma unroll
      for (int ni = 0; ni < 4; ++ni) {
        const int row0 = bm * 128 + wm + mi * 16 + quad * 4;
        const int col  = colbase + bcol[ni] + m16;
        const int nn = col - HIDDEN - NKVH * HDIM;
        const int hh = nn >> 7, d = nn & 127;
#pragma unroll
        for (int r = 0; r < 4; ++r) {
          const int m = row0 + r;
          const int b = m >> 11, s = m & 2047;
          vtbuf[(((size_t)(b * NKVH + hh)) * HDIM + d) * S_LEN + s] =
              __float2bfloat16(acc[mi][ni][r]);
        }
      }
  }
}

// ---------------- Attention phase A: split-K partials, max-free softmax ------
// Balanced chunks (<=27 iters), descending dispatch. nch==1 tiles are final:
// divide by row-sum and write abuf directly (skip partial round-trip).
__global__ __launch_bounds__(256) void attn_partial(const bf16* __restrict__ qbuf,
                                                    const bf16* __restrict__ kbuf,
                                                    const bf16* __restrict__ vtbuf,
                                                    unsigned short* __restrict__ pnum,
                                                    float* __restrict__ plsum,
                                                    bf16* __restrict__ abuf)
{
  __shared__ unsigned short Ks[2][4096];
  __shared__ unsigned short Vs[2][4096];
  __shared__ unsigned short Ps[4][1280];
  const int sidx = 110 - blockIdx.x;       // descending dispatch
  int i2, c, nch;
  if (sidx < 27)      { i2 = sidx;                     c = 0;              nch = 1; }
  else if (sidx < 81) { i2 = 27 + ((sidx - 27) >> 1);  c = (sidx - 27) & 1; nch = 2; }
  else                { i2 = 54 + (sidx - 81) / 3;     c = (sidx - 81) % 3; nch = 3; }
  const int len = i2 + 1;
  const int k0 = (c * len) / nch, k1 = ((c + 1) * len) / nch;
  const int kvh = blockIdx.y, b = blockIdx.z;
  const int t = threadIdx.x, w = t >> 6, lane = t & 63;
  const int m16 = lane & 15, quad = lane >> 4;
  const int h = kvh * 4 + w;

  const bf16* Qp = qbuf + (((size_t)(b * NHEADS + h)) * S_LEN + i2 * 32 + m16) * HDIM;
  short8 qf[2][4];
#pragma unroll
  for (int T = 0; T < 2; ++T)
#pragma unroll
    for (int cc = 0; cc < 4; ++cc)
      qf[T][cc] = *reinterpret_cast<const short8*>(Qp + (size_t)T * 16 * HDIM + cc * 32 + quad * 8);

  const bf16* Kp  = kbuf  + ((size_t)(b * NKVH + kvh)) * S_LEN * HDIM;
  const bf16* Vtp = vtbuf + ((size_t)(b * NKVH + kvh)) * HDIM * S_LEN;

  const int kk = lane >> 4, cK = lane & 15;
  const int rKa = w * 8 + kk, rKb = rKa + 4;
  const int offKa = rKa * 128 + ((cK ^ (rKa & 7)) * 8);
  const int offKb = rKb * 128 + ((cK ^ (rKb & 7)) * 8);
  const int dd = lane >> 2, cV = lane & 3;
  const int dVa = w * 32 + dd, dVb = dVa + 16;
  const int offVa = dVa * 2048 + ((cV ^ ((dVa >> 1) & 3)) * 8);
  const int offVb = dVb * 2048 + ((cV ^ ((dVb >> 1) & 3)) * 8);

  const floatx4 zf = {0.f, 0.f, 0.f, 0.f};
  floatx4 oacc[2][8];
#pragma unroll
  for (int T = 0; T < 2; ++T)
#pragma unroll
    for (int d = 0; d < 8; ++d) oacc[T][d] = zf;
  floatx4 lacc[2] = {zf, zf};
  unsigned short ones_s[8] = {0x3F80,0x3F80,0x3F80,0x3F80,0x3F80,0x3F80,0x3F80,0x3F80};
  const short8 ones = *reinterpret_cast<short8*>(ones_s);

  unsigned short* Pw = &Ps[w][0];

  {
    const int ks = k0 * 32;
    async_copy16(Kp + (size_t)ks * 128 + offKa, &Ks[0][w * 1024]);
    async_copy16(Kp + (size_t)ks * 128 + offKb, &Ks[0][w * 1024 + 512]);
    async_copy16(Vtp + ks + offVa, &Vs[0][w * 1024]);
    async_copy16(Vtp + ks + offVb, &Vs[0][w * 1024 + 512]);
  }
  __syncthreads();

  for (int ki = k0; ki < k1; ++ki) {
    const int buf = (ki - k0) & 1;
    if (ki + 1 < k1) {
      const int ks = (ki + 1) * 32;
      async_copy16(Kp + (size_t)ks * 128 + offKa, &Ks[buf ^ 1][w * 1024]);
      async_copy16(Kp + (size_t)ks * 128 + offKb, &Ks[buf ^ 1][w * 1024 + 512]);
      async_copy16(Vtp + ks + offVa, &Vs[buf ^ 1][w * 1024]);
      async_copy16(Vtp + ks + offVb, &Vs[buf ^ 1][w * 1024 + 512]);
    }
    const int ks = ki * 32;
    floatx4 s00 = zf, s01 = zf, s10 = zf, s11 = zf;
#pragma unroll
    for (int cc = 0; cc < 4; ++cc) {
      const int sw = ((cc * 4 + quad) ^ (m16 & 7)) * 8;
      short8 kf0 = *reinterpret_cast<const short8*>(&Ks[buf][m16 * 128 + sw]);
      short8 kf1 = *reinterpret_cast<const short8*>(&Ks[buf][(16 + m16) * 128 + sw]);
      s00 = __builtin_amdgcn_mfma_f32_16x16x32_bf16(qf[0][cc], kf0, s00, 0, 0, 0);
      s01 = __builtin_amdgcn_mfma_f32_16x16x32_bf16(qf[0][cc], kf1, s01, 0, 0, 0);
      s10 = __builtin_amdgcn_mfma_f32_16x16x32_bf16(qf[1][cc], kf0, s10, 0, 0, 0);
      s11 = __builtin_amdgcn_mfma_f32_16x16x32_bf16(qf[1][cc], kf1, s11, 0, 0, 0);
    }
#pragma unroll
    for (int T = 0; T < 2; ++T) {
      const floatx4& sa = T ? s10 : s00;
      const floatx4& sb = T ? s11 : s01;
#pragma unroll
      for (int r = 0; r < 4; ++r) {
        const int row = i2 * 32 + T * 16 + quad * 4 + r;
        const float p0 = (ks + m16      > row) ? 0.f : __expf(sa[r]);
        const float p1 = (ks + 16 + m16 > row) ? 0.f : __expf(sb[r]);
        Pw[(T * 16 + quad * 4 + r) * 40 + m16]      = cvt1(p0);
        Pw[(T * 16 + quad * 4 + r) * 40 + 16 + m16] = cvt1(p1);
      }
    }
    const short8 pa0 = *reinterpret_cast<const short8*>(&Pw[m16 * 40 + quad * 8]);
    const short8 pa1 = *reinterpret_cast<const short8*>(&Pw[(16 + m16) * 40 + quad * 8]);
    lacc[0] = __builtin_amdgcn_mfma_f32_16x16x32_bf16(pa0, ones, lacc[0], 0, 0, 0);
    lacc[1] = __builtin_amdgcn_mfma_f32_16x16x32_bf16(pa1, ones, lacc[1], 0, 0, 0);
#pragma unroll
    for (int dt = 0; dt < 8; ++dt) {
      short8 vfr = *reinterpret_cast<const short8*>(
          &Vs[buf][(dt * 16 + m16) * 32 + ((quad ^ ((m16 >> 1) & 3)) * 8)]);
      oacc[0][dt] = __builtin_amdgcn_mfma_f32_16x16x32_bf16(pa0, vfr, oacc[0][dt], 0, 0, 0);
      oacc[1][dt] = __builtin_amdgcn_mfma_f32_16x16x32_bf16(pa1, vfr, oacc[1][dt], 0, 0, 0);
    }
    __syncthreads();
  }

  if (nch == 1) {
    // final: divide by row-sum, write abuf directly
#pragma unroll
    for (int T = 0; T < 2; ++T) {
      float invl[4];
#pragma unroll
      for (int r = 0; r < 4; ++r) invl[r] = 1.0f / lacc[T][r];
      bf16* op = abuf + (((size_t)b * S_LEN + i2 * 32 + T * 16 + quad * 4) * NHEADS + h) * HDIM + m16;
#pragma unroll
      for (int dt = 0; dt < 8; ++dt)
#pragma unroll
        for (int r = 0; r < 4; ++r)
          op[(size_t)r * NHEADS * HDIM + dt * 16] = __float2bfloat16(oacc[T][dt][r] * invl[r]);
    }
  } else {
    const int b0 = (i2 < 54) ? (27 + 2 * (i2 - 27)) : (81 + 3 * (i2 - 54));
    const int slot = (b * NHEADS + h) * 111 + b0 + c;
    unsigned short* np = pnum + (size_t)slot * 4096;
#pragma unroll
    for (int T = 0; T < 2; ++T)
#pragma unroll
      for (int dt = 0; dt < 8; ++dt)
#pragma unroll
        for (int r = 0; r < 4; ++r)
          np[(T * 16 + quad * 4 + r) * 128 + dt * 16 + m16] = cvt1(oacc[T][dt][r]);
    if (m16 == 0) {
#pragma unroll
      for (int T = 0; T < 2; ++T)
#pragma unroll
        for (int r = 0; r < 4; ++r)
          plsum[slot * 32 + T * 16 + quad * 4 + r] = lacc[T][r];
    }
  }
}

// ---------------- Attention phase B: combine multi-chunk tiles only ----------
__global__ __launch_bounds__(256) void attn_combine(const unsigned short* __restrict__ pnum,
                                                    const float* __restrict__ plsum,
                                                    bf16* __restrict__ abuf)
{
  const int i = 54 + blockIdx.x;                     // 16-row tiles 54..127
  const int h = blockIdx.y, b = blockIdx.z;
  const int i2 = i >> 1, lr0 = (i & 1) * 16;
  const int t = threadIdx.x, row16 = t >> 4, c0 = (t & 15) * 8;
  const int lr = lr0 + row16;
  const int nch = (i2 < 54) ? 2 : 3;
  const int b0  = (i2 < 54) ? (27 + 2 * (i2 - 27)) : (81 + 3 * (i2 - 54));
  const int hb = (b * NHEADS + h) * 111 + b0;
  float acc[8] = {0.f,0.f,0.f,0.f,0.f,0.f,0.f,0.f};
  float lsum = 0.f;
  for (int c = 0; c < nch; ++c) {
    const unsigned short* np = pnum + (size_t)(hb + c) * 4096 + lr * 128 + c0;
    const short8 v = *reinterpret_cast<const short8*>(np);
#pragma unroll
    for (int j = 0; j < 8; ++j) acc[j] += us2f(((unsigned short*)&v)[j]);
    lsum += plsum[(hb + c) * 32 + lr];
  }
  const float invl = 1.0f / lsum;
  unsigned short o[8];
#pragma unroll
  for (int j = 0; j < 8; ++j) o[j] = cvt1(acc[j] * invl);
  *reinterpret_cast<short8*>(abuf + (((size_t)b * S_LEN + i * 16 + row16) * NHEADS + h) * HDIM + c0)
      = *reinterpret_cast<short8*>(o);
}

extern "C" void kernel_launch(void* const* d_in, const int* in_sizes, int n_in,
                              void* d_out, int out_size, void* d_ws, size_t ws_size,
                              hipStream_t stream) {
  const float* hidden_f = (const float*)d_in[0];
  const float* wqkv_f   = (const float*)d_in[1];
  const float* wout_f   = (const float*)d_in[2];
  float* out = (float*)d_out;

  char* ws = (char*)d_ws;
  bf16* hbf    = (bf16*)(ws);                    // [4096,2048]   (dead after gemm0)
  bf16* wqkvbf = (bf16*)(ws + 16777216);         // [3072,2048]   (dead after gemm0)
  bf16* woutbf = (bf16*)(ws + 29360128);         // [2048,2048]
  bf16* qbuf   = (bf16*)(ws + 37748736);         // [B,NH,S,HD]
  bf16* kbuf   = (bf16*)(ws + 54525952);         // [B,NKV,S,HD]
  bf16* vtbuf  = (bf16*)(ws + 58720256);         // [B,NKV,HD,S]
  bf16* abuf   = (bf16*)(ws + 62914560);         // [B,S,NH,HD]
  unsigned short* pnum = (unsigned short*)(ws);  // overlay: 3552 x 8KB = 29.1 MB
  float* plsum = (float*)(ws + 79691776);        // 3552 x 32 fp32 (0.45 MB)

  cvt_all<<<9216, 256, 0, stream>>>(hidden_f, wqkv_f, wout_f, (unsigned short*)ws);

  gemm_bt<0><<<dim3(24, 32), 256, 0, stream>>>(hbf, wqkvbf, 4096, 3072, 2048,
                                               qbuf, kbuf, vtbuf, nullptr);
  attn_partial<<<dim3(111, 4, 2), 256, 0, stream>>>(qbuf, kbuf, vtbuf, pnum, plsum, abuf);
  attn_combine<<<dim3(74, 16, 2), 256, 0, stream>>>(pnum, plsum, abuf);
  gemm_bt<1><<<dim3(16, 32), 256, 0, stream>>>(abuf, woutbf, 4096, 2048, 2048,
                                               nullptr, nullptr, nullptr, out);
}